// Round 11
// baseline (793.641 us; speedup 1.0000x reference)
//
#include <hip/hip_runtime.h>

typedef unsigned short ushort_t;
typedef unsigned int   uint_t;

typedef ushort_t u16x8  __attribute__((ext_vector_type(8)));
typedef __bf16   bf16x8 __attribute__((ext_vector_type(8)));
typedef float    f32x4  __attribute__((ext_vector_type(4)));

#define DIMSZ 1024

__device__ __forceinline__ ushort_t f2bf(float f) {
  uint_t u = __builtin_bit_cast(uint_t, f);
  u += 0x7fffu + ((u >> 16) & 1u);          // RNE
  return (ushort_t)(u >> 16);
}
__device__ __forceinline__ float bf2f(ushort_t h) {
  uint_t u = ((uint_t)h) << 16;
  return __builtin_bit_cast(float, u);
}
__device__ __forceinline__ void lds_load16(const void* g, void* l) {
  __builtin_amdgcn_global_load_lds((const __attribute__((address_space(1))) void*)g,
                                   (__attribute__((address_space(3))) void*)l, 16, 0, 0);
}
#define SCHED0() __builtin_amdgcn_sched_barrier(0)
#define WBAR() do { SCHED0(); __builtin_amdgcn_s_barrier(); SCHED0(); } while (0)

// ---------- combined weight transpose + bf16 into Wall[4096][1024] ----------
__global__ __launch_bounds__(256) void wtrans4(const float* __restrict__ Wq,
                                               const float* __restrict__ Wkv,
                                               const float* __restrict__ Wp,
                                               ushort_t* __restrict__ dst) {
  __shared__ ushort_t tile[32][33];
  const int bx = blockIdx.x, by = blockIdx.y;
  const int n0 = bx * 32;
  const float* src; int ld, c0;
  if (n0 < 1024)      { src = Wq;  ld = 1024; c0 = n0; }
  else if (n0 < 3072) { src = Wkv; ld = 2048; c0 = n0 - 1024; }
  else                { src = Wp;  ld = 1024; c0 = n0 - 3072; }
  const int tx = threadIdx.x & 31, ty = threadIdx.x >> 5;
#pragma unroll
  for (int i = 0; i < 32; i += 8)
    tile[ty + i][tx] = f2bf(src[(size_t)(by * 32 + ty + i) * ld + c0 + tx]);
  __syncthreads();
#pragma unroll
  for (int i = 0; i < 32; i += 8)
    dst[(size_t)(n0 + ty + i) * 1024 + by * 32 + tx] = tile[tx][ty + i];
}

// ---------- fp32 -> bf16 convert, x and y, block-range split ----------
// Blocks [0, G/2) stream x, [G/2, G) stream y. 64B nontemporal reads,
// 32B cached writes (keep bf16 L3-resident for the GEMMs), 4 iterations.
__global__ __launch_bounds__(256) void cvt2(const float* __restrict__ x,
                                            const float* __restrict__ y,
                                            ushort_t* __restrict__ xb,
                                            ushort_t* __restrict__ yb) {
  const int halfb = gridDim.x >> 1;
  const float* s; ushort_t* d;
  int b = blockIdx.x;
  if (b < halfb) { s = x; d = xb; }
  else           { s = y; d = yb; b -= halfb; }
  const size_t ngrp = (size_t)65536 * 1024 / 16;      // 4M groups of 16
  const size_t stride = (size_t)halfb * 256;
  for (size_t i = (size_t)b * 256 + threadIdx.x; i < ngrp; i += stride) {
    const f32x4* p = (const f32x4*)(s + i * 16);
    f32x4 f0 = __builtin_nontemporal_load(p);
    f32x4 f1 = __builtin_nontemporal_load(p + 1);
    f32x4 f2 = __builtin_nontemporal_load(p + 2);
    f32x4 f3 = __builtin_nontemporal_load(p + 3);
    u16x8 o0, o1;
#pragma unroll
    for (int j = 0; j < 4; ++j) {
      o0[j] = f2bf(f0[j]); o0[4 + j] = f2bf(f1[j]);
      o1[j] = f2bf(f2[j]); o1[4 + j] = f2bf(f3[j]);
    }
    *(u16x8*)(d + i * 16) = o0;
    *(u16x8*)(d + i * 16 + 8) = o1;
  }
}

// ---------- softmax over 16 heads, in place on dots[B,16] ----------
__global__ __launch_bounds__(256) void softmax16(float* __restrict__ d) {
  const int row = blockIdx.x * 256 + threadIdx.x;
  f32x4 v[4];
#pragma unroll
  for (int i = 0; i < 4; ++i) v[i] = *(const f32x4*)(d + (size_t)row * 16 + i * 4);
  float m = v[0][0];
#pragma unroll
  for (int i = 0; i < 4; ++i)
#pragma unroll
    for (int j = 0; j < 4; ++j) m = fmaxf(m, v[i][j]);
  float sum = 0.f;
#pragma unroll
  for (int i = 0; i < 4; ++i)
#pragma unroll
    for (int j = 0; j < 4; ++j) { v[i][j] = expf(v[i][j] - m); sum += v[i][j]; }
  const float r = 1.f / sum;
#pragma unroll
  for (int i = 0; i < 4; ++i) {
#pragma unroll
    for (int j = 0; j < 4; ++j) v[i][j] *= r;
    *(f32x4*)(d + (size_t)row * 16 + i * 4) = v[i];
  }
}

// ---------- 256x256x(BK=64) 8-wave 8-phase bf16 GEMM (proven core, frozen) ----------
// EPI 0: C bf16 (ldc).  EPI 1: C f32 + bias (ldc=1024).
// EPI 2: no C write; dots[row,head] = 0.015625 * sum(acc * k), k from kvp [M,1024].
// EPI 3: C bf16, acc scaled by attn[row, head] (attn passed via `bias`).
template <int EPI>
__global__ __launch_bounds__(512, 2) void gemm8(const ushort_t* __restrict__ A,
                                                const ushort_t* __restrict__ Bt,
                                                void* __restrict__ Cv,
                                                const float* __restrict__ bias,
                                                const ushort_t* __restrict__ kvp,
                                                float* __restrict__ dots,
                                                int ldc, int ncol_lg2) {
  __shared__ ushort_t lds[65536];
  const int t = threadIdx.x;
  const int nb8 = gridDim.x >> 3;                       // XCD-aware bijective swizzle
  const int nbid = (blockIdx.x & 7) * nb8 + (blockIdx.x >> 3);
  const int n0 = (nbid & ((1 << ncol_lg2) - 1)) * 256;
  const int m0 = (nbid >> ncol_lg2) * 256;
  const int w = t >> 6, lane = t & 63;
  const int wm = w >> 2, wn = w & 3;
  const int lr = lane & 15, lk = lane >> 4;
  const int w512 = w * 512;

  // staging source (per-thread, swizzle pre-applied to global column)
  const int srow = w * 8 + (lane >> 3);                 // 0..63 within a 64-row block
  const int scsw = ((lane & 7) * 16) ^ ((srow & 7) << 4);
  const ushort_t* aS = A + (size_t)(m0 + srow) * DIMSZ + (scsw >> 1);
  const ushort_t* bS = Bt + (size_t)(n0 + srow) * DIMSZ + (scsw >> 1);

  // fragment ds_read offsets (elems), swizzled
  const int cbe0 = (((lk * 16)) ^ ((lr & 7) << 4)) >> 1;         // ks=0
  const int cbe1 = ((64 + lk * 16) ^ ((lr & 7) << 4)) >> 1;      // ks=1
  const int aRB = lr * 64;
  const int bRB = 32768 + (wn * 64 + lr) * 64;

  f32x4 acc[8][4];
  const f32x4 zf = {0.f, 0.f, 0.f, 0.f};
#pragma unroll
  for (int i = 0; i < 8; ++i)
#pragma unroll
    for (int j = 0; j < 4; ++j) acc[i][j] = zf;
  bf16x8 a[4][2], b0[2][2], b1[2][2];

  // A half h (=mq) -> blocks {h, h+2}; B half h -> rows [h*128, h*128+128)
#define STAGE_A(cc, hh, tt) do {                                          \
    const ushort_t* s_ = aS + (size_t)(hh) * 65536 + (tt) * 64;           \
    ushort_t* d_ = lds + (cc) * 16384 + (hh) * 4096 + w512;               \
    lds_load16(s_, d_);                                                   \
    lds_load16(s_ + 131072, d_ + 8192); } while (0)
#define STAGE_B(cc, hh, tt) do {                                          \
    const ushort_t* s_ = bS + (size_t)(hh) * 131072 + (tt) * 64;          \
    ushort_t* d_ = lds + 32768 + (cc) * 16384 + (hh) * 8192 + w512;       \
    lds_load16(s_, d_);                                                   \
    lds_load16(s_ + 65536, d_ + 4096); } while (0)
#define LDA(cc, mq) do {                                                  \
    const ushort_t* Lp = lds + (cc) * 16384 + (wm * 2 + (mq)) * 4096 + aRB; \
    _Pragma("unroll") for (int j = 0; j < 4; ++j) {                       \
      a[j][0] = *(const bf16x8*)(Lp + j * 1024 + cbe0);                   \
      a[j][1] = *(const bf16x8*)(Lp + j * 1024 + cbe1); } } while (0)
#define LDB(cc, dst, nq) do {                                             \
    const ushort_t* Lp = lds + (cc) * 16384 + bRB + (nq) * 2048;          \
    _Pragma("unroll") for (int ni = 0; ni < 2; ++ni) {                    \
      dst[ni][0] = *(const bf16x8*)(Lp + ni * 1024 + cbe0);               \
      dst[ni][1] = *(const bf16x8*)(Lp + ni * 1024 + cbe1); } } while (0)
#define MMQ(mb, B, nb) do {                                               \
    _Pragma("unroll") for (int j = 0; j < 4; ++j)                         \
    _Pragma("unroll") for (int ni = 0; ni < 2; ++ni)                      \
    _Pragma("unroll") for (int ks = 0; ks < 2; ++ks)                      \
      acc[(mb) + j][(nb) + ni] = __builtin_amdgcn_mfma_f32_16x16x32_bf16( \
          a[j][ks], B[ni][ks], acc[(mb) + j][(nb) + ni], 0, 0, 0); } while (0)
#define TILE(S1, S2, VM, tv, c, nxt) do {                                 \
    LDA(c, 0); LDB(c, b0, 0);                                             \
    if (S1) STAGE_A(nxt, 1, (tv) + 1);                                    \
    WBAR();                                                               \
    __builtin_amdgcn_s_setprio(1); MMQ(0, b0, 0); __builtin_amdgcn_s_setprio(0); \
    WBAR();                                                               \
    LDB(c, b1, 1);                                                        \
    if (S2) STAGE_A(c, 0, (tv) + 2);                                      \
    WBAR();                                                               \
    __builtin_amdgcn_s_setprio(1); MMQ(0, b1, 2); __builtin_amdgcn_s_setprio(0); \
    WBAR();                                                               \
    LDA(c, 1);                                                            \
    if (S2) STAGE_B(c, 0, (tv) + 2);                                      \
    WBAR();                                                               \
    __builtin_amdgcn_s_setprio(1); MMQ(4, b1, 2); __builtin_amdgcn_s_setprio(0); \
    WBAR();                                                               \
    if (S2) STAGE_B(c, 1, (tv) + 2);                                      \
    if ((VM) == 6) { asm volatile("s_waitcnt vmcnt(6)" ::: "memory"); }   \
    else if ((VM) == 0) { asm volatile("s_waitcnt vmcnt(0)" ::: "memory"); } \
    WBAR();                                                               \
    __builtin_amdgcn_s_setprio(1); MMQ(4, b0, 0); __builtin_amdgcn_s_setprio(0); \
    WBAR();                                                               \
  } while (0)

  // prologue: tile0 {Ah0,Ah1,Bh0,Bh1}, tile1 {Ah0,Bh0,Bh1}; leave tile1's 3 halves in flight
  STAGE_A(0, 0, 0); STAGE_A(0, 1, 0); STAGE_B(0, 0, 0); STAGE_B(0, 1, 0);
  STAGE_A(1, 0, 1); STAGE_B(1, 0, 1); STAGE_B(1, 1, 1);
  asm volatile("s_waitcnt vmcnt(6)" ::: "memory");
  WBAR();

  for (int tt = 0; tt < 7; ++tt) {
    const int t0 = tt * 2;
    TILE(1, 1, 6, t0, 0, 1);
    TILE(1, 1, 6, t0 + 1, 1, 0);
  }
  TILE(1, 0, 0, 14, 0, 1);
  TILE(0, 0, -1, 15, 1, 0);

#undef TILE
#undef MMQ
#undef LDB
#undef LDA
#undef STAGE_B
#undef STAGE_A

  if constexpr (EPI == 0 || EPI == 3) {
    // bf16 epilogue: (EPI3: scale acc by attn[row, head] first) then bounce
    // through per-wave 16KB LDS slice for 128B-coalesced stores.
    ushort_t* Cp = (ushort_t*)Cv;
    ushort_t* ep = lds + w * 8192;
    const int h = (n0 >> 6) + wn;     // EPI3: wave's 64 cols = one head
#pragma unroll
    for (int mq = 0; mq < 2; ++mq)
#pragma unroll
      for (int j = 0; j < 4; ++j)
#pragma unroll
        for (int r = 0; r < 4; ++r) {
          const int row = mq * 64 + j * 16 + lk * 4 + r;
          float sc = 1.f;
          if (EPI == 3)
            sc = bias[(size_t)(m0 + wm * 128 + row) * 16 + h];
#pragma unroll
          for (int ni = 0; ni < 4; ++ni) {
            const int ce = ((ni * 16 + lr) * 2) ^ ((row & 7) << 4);
            ep[row * 64 + (ce >> 1)] = f2bf(acc[mq * 4 + j][ni][r] * sc);
          }
        }
#pragma unroll
    for (int rr = 0; rr < 16; ++rr) {
      const int row = rr * 8 + (lane >> 3);
      const int ce = ((lane & 7) * 16) ^ ((lane >> 3) << 4);
      u16x8 vv = *(const u16x8*)(ep + row * 64 + (ce >> 1));
      *(u16x8*)(Cp + (size_t)(m0 + wm * 128 + row) * ldc + n0 + wn * 64 + (lane & 7) * 8) = vv;
    }
  } else if constexpr (EPI == 1) {
    float* Op = (float*)Cv;
    float bb[4];
#pragma unroll
    for (int ni = 0; ni < 4; ++ni) bb[ni] = bias[n0 + wn * 64 + ni * 16 + lr];
#pragma unroll
    for (int mq = 0; mq < 2; ++mq)
#pragma unroll
      for (int j = 0; j < 4; ++j)
#pragma unroll
        for (int ni = 0; ni < 4; ++ni)
#pragma unroll
          for (int r = 0; r < 4; ++r)
            Op[(size_t)(m0 + wm * 128 + mq * 64 + j * 16 + lk * 4 + r) * 1024 +
               n0 + wn * 64 + ni * 16 + lr] = acc[mq * 4 + j][ni][r] + bb[ni];
  } else {
    // dots epilogue: wave's 64 cols = head h; stage k[128 rows][64] from kb [M,1024]
    // into LDS with XOR swizzle (pre-swizzled source, swizzled read -> 2-way max),
    // dot with acc along cols, width-16 shfl reduce, write dots[row, h].
    const int h = (n0 >> 6) + wn;
    ushort_t* kw = lds + w * 8192;
    const int rsub = lane >> 3;
    const int csw = (((lane & 7) * 16) ^ (rsub << 4)) >> 1;   // swizzled src col (elems)
    const ushort_t* kS = kvp + (size_t)(m0 + wm * 128 + rsub) * 1024 + h * 64 + csw;
#pragma unroll
    for (int i = 0; i < 16; ++i)
      lds_load16(kS + (size_t)i * 8 * 1024, kw + i * 512);
    asm volatile("s_waitcnt vmcnt(0)" ::: "memory");
#pragma unroll
    for (int mq = 0; mq < 2; ++mq)
#pragma unroll
      for (int j = 0; j < 4; ++j)
#pragma unroll
        for (int r = 0; r < 4; ++r) {
          const int row = mq * 64 + j * 16 + lk * 4 + r;
          float p = 0.f;
#pragma unroll
          for (int ni = 0; ni < 4; ++ni) {
            const int ce = (((ni * 16 + lr) * 2) ^ ((row & 7) << 4)) >> 1;
            p += acc[mq * 4 + j][ni][r] * bf2f(kw[row * 64 + ce]);
          }
#pragma unroll
          for (int off = 1; off < 16; off <<= 1) p += __shfl_xor(p, off, 16);
          if (lr == 0)
            dots[(size_t)(m0 + wm * 128 + row) * 16 + h] = p * 0.015625f;
        }
  }
}

extern "C" void kernel_launch(void* const* d_in, const int* in_sizes, int n_in,
                              void* d_out, int out_size, void* d_ws, size_t ws_size,
                              hipStream_t stream) {
  const float* x   = (const float*)d_in[0];
  const float* y   = (const float*)d_in[1];
  const float* Wq  = (const float*)d_in[3];
  const float* Wkv = (const float*)d_in[4];
  const float* Wp  = (const float*)d_in[5];
  const float* bp  = (const float*)d_in[6];
  (void)in_sizes; (void)n_in; (void)out_size; (void)ws_size;

  char* ws = (char*)d_ws;                               // 396 MiB total
  ushort_t* Wall  = (ushort_t*)(ws);                    //   8 MiB [4096][1024] = [Wq|Wk|Wv|Wp]
  float*    dotsb = (float*)   (ws + (8ull   << 20));   //   4 MiB [65536][16] dots->attn
  ushort_t* yb    = (ushort_t*)(ws + (12ull  << 20));   // 128 MiB y bf16 (alive thru v-gemm)
  ushort_t* xb    = (ushort_t*)(ws + (140ull << 20));   // 128 MiB x bf16 -> reused as ab
  ushort_t* kb    = (ushort_t*)(ws + (268ull << 20));   // 128 MiB k bf16

  const ushort_t* Wqt = Wall;
  const ushort_t* Wkt = Wall + (size_t)1024 * 1024;
  const ushort_t* Wvt = Wall + (size_t)2048 * 1024;
  const ushort_t* Wpt = Wall + (size_t)3072 * 1024;

  // all weights -> bf16, transposed, one launch
  wtrans4<<<dim3(128, 32), 256, 0, stream>>>(Wq, Wkv, Wp, Wall);

  // x,y -> bf16, block-range split, nontemporal reads
  cvt2<<<8192, 256, 0, stream>>>(x, y, xb, yb);

  // k = yb @ Wk
  gemm8<0><<<1024, 512, 0, stream>>>(yb, Wkt, kb, nullptr, nullptr, nullptr, 1024, 2);

  // dots = per-head <q, k>: q-GEMM with fused dots epilogue (q never materialized)
  gemm8<2><<<1024, 512, 0, stream>>>(xb, Wqt, nullptr, nullptr, kb, dotsb, 1024, 2);

  // softmax over heads, in place
  softmax16<<<256, 256, 0, stream>>>(dotsb);

  // ab = attn .* (yb @ Wv)   — v never materialized unscaled
  gemm8<3><<<1024, 512, 0, stream>>>(yb, Wvt, xb, dotsb, nullptr, nullptr, 1024, 2);

  // out = ab @ Wproj + bproj (f32)
  gemm8<1><<<1024, 512, 0, stream>>>(xb, Wpt, d_out, bp, nullptr, nullptr, 1024, 2);
}

// Round 12
// 742.340 us; speedup vs baseline: 1.0691x; 1.0691x over previous
//
#include <hip/hip_runtime.h>

typedef unsigned short ushort_t;
typedef unsigned int   uint_t;

typedef ushort_t u16x8  __attribute__((ext_vector_type(8)));
typedef __bf16   bf16x8 __attribute__((ext_vector_type(8)));
typedef float    f32x4  __attribute__((ext_vector_type(4)));

#define DIMSZ 1024

__device__ __forceinline__ ushort_t f2bf(float f) {
  uint_t u = __builtin_bit_cast(uint_t, f);
  u += 0x7fffu + ((u >> 16) & 1u);          // RNE
  return (ushort_t)(u >> 16);
}
__device__ __forceinline__ float bf2f(ushort_t h) {
  uint_t u = ((uint_t)h) << 16;
  return __builtin_bit_cast(float, u);
}
__device__ __forceinline__ void lds_load16(const void* g, void* l) {
  __builtin_amdgcn_global_load_lds((const __attribute__((address_space(1))) void*)g,
                                   (__attribute__((address_space(3))) void*)l, 16, 0, 0);
}
#define SCHED0() __builtin_amdgcn_sched_barrier(0)
#define WBAR() do { SCHED0(); __builtin_amdgcn_s_barrier(); SCHED0(); } while (0)

// ---------- combined weight transpose + bf16 into Wall[4096][1024] ----------
__global__ __launch_bounds__(256) void wtrans4(const float* __restrict__ Wq,
                                               const float* __restrict__ Wkv,
                                               const float* __restrict__ Wp,
                                               ushort_t* __restrict__ dst) {
  __shared__ ushort_t tile[32][33];
  const int bx = blockIdx.x, by = blockIdx.y;
  const int n0 = bx * 32;
  const float* src; int ld, c0;
  if (n0 < 1024)      { src = Wq;  ld = 1024; c0 = n0; }
  else if (n0 < 3072) { src = Wkv; ld = 2048; c0 = n0 - 1024; }
  else                { src = Wp;  ld = 1024; c0 = n0 - 3072; }
  const int tx = threadIdx.x & 31, ty = threadIdx.x >> 5;
#pragma unroll
  for (int i = 0; i < 32; i += 8)
    tile[ty + i][tx] = f2bf(src[(size_t)(by * 32 + ty + i) * ld + c0 + tx]);
  __syncthreads();
#pragma unroll
  for (int i = 0; i < 32; i += 8)
    dst[(size_t)(n0 + ty + i) * 1024 + by * 32 + tx] = tile[tx][ty + i];
}

// ---------- fp32 -> bf16 convert for BOTH x and y (round-10 proven form) ----------
__global__ __launch_bounds__(256) void cvt2(const float* __restrict__ x,
                                            const float* __restrict__ y,
                                            ushort_t* __restrict__ xb,
                                            ushort_t* __restrict__ yb) {
  const size_t half = (size_t)65536 * 1024 / 8;     // 8M groups of 8 per tensor
  const size_t n8 = half * 2;
  const size_t stride = (size_t)gridDim.x * 256;
  for (size_t g = (size_t)blockIdx.x * 256 + threadIdx.x; g < n8; g += stride) {
    const float* s; ushort_t* d; size_t i;
    if (g < half) { s = x; d = xb; i = g; } else { s = y; d = yb; i = g - half; }
    f32x4 f0 = *(const f32x4*)(s + i * 8);
    f32x4 f1 = *(const f32x4*)(s + i * 8 + 4);
    u16x8 o;
#pragma unroll
    for (int j = 0; j < 4; ++j) { o[j] = f2bf(f0[j]); o[4 + j] = f2bf(f1[j]); }
    *(u16x8*)(d + i * 8) = o;
  }
}

// ---------- softmax over 16 heads, in place on dots[B,16] ----------
__global__ __launch_bounds__(256) void softmax16(float* __restrict__ d) {
  const int row = blockIdx.x * 256 + threadIdx.x;
  f32x4 v[4];
#pragma unroll
  for (int i = 0; i < 4; ++i) v[i] = *(const f32x4*)(d + (size_t)row * 16 + i * 4);
  float m = v[0][0];
#pragma unroll
  for (int i = 0; i < 4; ++i)
#pragma unroll
    for (int j = 0; j < 4; ++j) m = fmaxf(m, v[i][j]);
  float sum = 0.f;
#pragma unroll
  for (int i = 0; i < 4; ++i)
#pragma unroll
    for (int j = 0; j < 4; ++j) { v[i][j] = expf(v[i][j] - m); sum += v[i][j]; }
  const float r = 1.f / sum;
#pragma unroll
  for (int i = 0; i < 4; ++i) {
#pragma unroll
    for (int j = 0; j < 4; ++j) v[i][j] *= r;
    *(f32x4*)(d + (size_t)row * 16 + i * 4) = v[i];
  }
}

// ---------- 256x256x(BK=64) 8-wave 8-phase bf16 GEMM (proven core, frozen) ----------
// EPI 0: C bf16 (ldc).  EPI 1: C f32 + bias (ldc=1024), nontemporal stores.
// EPI 2: no C write; dots[row,head] = 0.015625 * sum(acc * k), k from kvp [M,1024].
// EPI 3: C bf16, acc scaled by attn[row, head] (attn passed via `bias`).
template <int EPI>
__global__ __launch_bounds__(512, 2) void gemm8(const ushort_t* __restrict__ A,
                                                const ushort_t* __restrict__ Bt,
                                                void* __restrict__ Cv,
                                                const float* __restrict__ bias,
                                                const ushort_t* __restrict__ kvp,
                                                float* __restrict__ dots,
                                                int ldc, int ncol_lg2) {
  __shared__ ushort_t lds[65536];
  const int t = threadIdx.x;
  const int nb8 = gridDim.x >> 3;                       // XCD-aware bijective swizzle
  const int nbid = (blockIdx.x & 7) * nb8 + (blockIdx.x >> 3);
  const int n0 = (nbid & ((1 << ncol_lg2) - 1)) * 256;
  const int m0 = (nbid >> ncol_lg2) * 256;
  const int w = t >> 6, lane = t & 63;
  const int wm = w >> 2, wn = w & 3;
  const int lr = lane & 15, lk = lane >> 4;
  const int w512 = w * 512;

  // staging source (per-thread, swizzle pre-applied to global column)
  const int srow = w * 8 + (lane >> 3);                 // 0..63 within a 64-row block
  const int scsw = ((lane & 7) * 16) ^ ((srow & 7) << 4);
  const ushort_t* aS = A + (size_t)(m0 + srow) * DIMSZ + (scsw >> 1);
  const ushort_t* bS = Bt + (size_t)(n0 + srow) * DIMSZ + (scsw >> 1);

  // fragment ds_read offsets (elems), swizzled
  const int cbe0 = (((lk * 16)) ^ ((lr & 7) << 4)) >> 1;         // ks=0
  const int cbe1 = ((64 + lk * 16) ^ ((lr & 7) << 4)) >> 1;      // ks=1
  const int aRB = lr * 64;
  const int bRB = 32768 + (wn * 64 + lr) * 64;

  f32x4 acc[8][4];
  const f32x4 zf = {0.f, 0.f, 0.f, 0.f};
#pragma unroll
  for (int i = 0; i < 8; ++i)
#pragma unroll
    for (int j = 0; j < 4; ++j) acc[i][j] = zf;
  bf16x8 a[4][2], b0[2][2], b1[2][2];

  // A half h (=mq) -> blocks {h, h+2}; B half h -> rows [h*128, h*128+128)
#define STAGE_A(cc, hh, tt) do {                                          \
    const ushort_t* s_ = aS + (size_t)(hh) * 65536 + (tt) * 64;           \
    ushort_t* d_ = lds + (cc) * 16384 + (hh) * 4096 + w512;               \
    lds_load16(s_, d_);                                                   \
    lds_load16(s_ + 131072, d_ + 8192); } while (0)
#define STAGE_B(cc, hh, tt) do {                                          \
    const ushort_t* s_ = bS + (size_t)(hh) * 131072 + (tt) * 64;          \
    ushort_t* d_ = lds + 32768 + (cc) * 16384 + (hh) * 8192 + w512;       \
    lds_load16(s_, d_);                                                   \
    lds_load16(s_ + 65536, d_ + 4096); } while (0)
#define LDA(cc, mq) do {                                                  \
    const ushort_t* Lp = lds + (cc) * 16384 + (wm * 2 + (mq)) * 4096 + aRB; \
    _Pragma("unroll") for (int j = 0; j < 4; ++j) {                       \
      a[j][0] = *(const bf16x8*)(Lp + j * 1024 + cbe0);                   \
      a[j][1] = *(const bf16x8*)(Lp + j * 1024 + cbe1); } } while (0)
#define LDB(cc, dst, nq) do {                                             \
    const ushort_t* Lp = lds + (cc) * 16384 + bRB + (nq) * 2048;          \
    _Pragma("unroll") for (int ni = 0; ni < 2; ++ni) {                    \
      dst[ni][0] = *(const bf16x8*)(Lp + ni * 1024 + cbe0);               \
      dst[ni][1] = *(const bf16x8*)(Lp + ni * 1024 + cbe1); } } while (0)
#define MMQ(mb, B, nb) do {                                               \
    _Pragma("unroll") for (int j = 0; j < 4; ++j)                         \
    _Pragma("unroll") for (int ni = 0; ni < 2; ++ni)                      \
    _Pragma("unroll") for (int ks = 0; ks < 2; ++ks)                      \
      acc[(mb) + j][(nb) + ni] = __builtin_amdgcn_mfma_f32_16x16x32_bf16( \
          a[j][ks], B[ni][ks], acc[(mb) + j][(nb) + ni], 0, 0, 0); } while (0)
#define TILE(S1, S2, VM, tv, c, nxt) do {                                 \
    LDA(c, 0); LDB(c, b0, 0);                                             \
    if (S1) STAGE_A(nxt, 1, (tv) + 1);                                    \
    WBAR();                                                               \
    __builtin_amdgcn_s_setprio(1); MMQ(0, b0, 0); __builtin_amdgcn_s_setprio(0); \
    WBAR();                                                               \
    LDB(c, b1, 1);                                                        \
    if (S2) STAGE_A(c, 0, (tv) + 2);                                      \
    WBAR();                                                               \
    __builtin_amdgcn_s_setprio(1); MMQ(0, b1, 2); __builtin_amdgcn_s_setprio(0); \
    WBAR();                                                               \
    LDA(c, 1);                                                            \
    if (S2) STAGE_B(c, 0, (tv) + 2);                                      \
    WBAR();                                                               \
    __builtin_amdgcn_s_setprio(1); MMQ(4, b1, 2); __builtin_amdgcn_s_setprio(0); \
    WBAR();                                                               \
    if (S2) STAGE_B(c, 1, (tv) + 2);                                      \
    if ((VM) == 6) { asm volatile("s_waitcnt vmcnt(6)" ::: "memory"); }   \
    else if ((VM) == 0) { asm volatile("s_waitcnt vmcnt(0)" ::: "memory"); } \
    WBAR();                                                               \
    __builtin_amdgcn_s_setprio(1); MMQ(4, b0, 0); __builtin_amdgcn_s_setprio(0); \
    WBAR();                                                               \
  } while (0)

  // prologue: tile0 {Ah0,Ah1,Bh0,Bh1}, tile1 {Ah0,Bh0,Bh1}; leave tile1's 3 halves in flight
  STAGE_A(0, 0, 0); STAGE_A(0, 1, 0); STAGE_B(0, 0, 0); STAGE_B(0, 1, 0);
  STAGE_A(1, 0, 1); STAGE_B(1, 0, 1); STAGE_B(1, 1, 1);
  asm volatile("s_waitcnt vmcnt(6)" ::: "memory");
  WBAR();

  for (int tt = 0; tt < 7; ++tt) {
    const int t0 = tt * 2;
    TILE(1, 1, 6, t0, 0, 1);
    TILE(1, 1, 6, t0 + 1, 1, 0);
  }
  TILE(1, 0, 0, 14, 0, 1);
  TILE(0, 0, -1, 15, 1, 0);

#undef TILE
#undef MMQ
#undef LDB
#undef LDA
#undef STAGE_B
#undef STAGE_A

  if constexpr (EPI == 0 || EPI == 3) {
    // bf16 epilogue: (EPI3: scale acc by attn[row, head] first) then bounce
    // through per-wave 16KB LDS slice for 128B-coalesced stores.
    ushort_t* Cp = (ushort_t*)Cv;
    ushort_t* ep = lds + w * 8192;
    const int h = (n0 >> 6) + wn;     // EPI3: wave's 64 cols = one head
#pragma unroll
    for (int mq = 0; mq < 2; ++mq)
#pragma unroll
      for (int j = 0; j < 4; ++j)
#pragma unroll
        for (int r = 0; r < 4; ++r) {
          const int row = mq * 64 + j * 16 + lk * 4 + r;
          float sc = 1.f;
          if (EPI == 3)
            sc = bias[(size_t)(m0 + wm * 128 + row) * 16 + h];
#pragma unroll
          for (int ni = 0; ni < 4; ++ni) {
            const int ce = ((ni * 16 + lr) * 2) ^ ((row & 7) << 4);
            ep[row * 64 + (ce >> 1)] = f2bf(acc[mq * 4 + j][ni][r] * sc);
          }
        }
#pragma unroll
    for (int rr = 0; rr < 16; ++rr) {
      const int row = rr * 8 + (lane >> 3);
      const int ce = ((lane & 7) * 16) ^ ((lane >> 3) << 4);
      u16x8 vv = *(const u16x8*)(ep + row * 64 + (ce >> 1));
      *(u16x8*)(Cp + (size_t)(m0 + wm * 128 + row) * ldc + n0 + wn * 64 + (lane & 7) * 8) = vv;
    }
  } else if constexpr (EPI == 1) {
    float* Op = (float*)Cv;
    float bb[4];
#pragma unroll
    for (int ni = 0; ni < 4; ++ni) bb[ni] = bias[n0 + wn * 64 + ni * 16 + lr];
#pragma unroll
    for (int mq = 0; mq < 2; ++mq)
#pragma unroll
      for (int j = 0; j < 4; ++j)
#pragma unroll
        for (int ni = 0; ni < 4; ++ni)
#pragma unroll
          for (int r = 0; r < 4; ++r)
            __builtin_nontemporal_store(
                acc[mq * 4 + j][ni][r] + bb[ni],
                Op + (size_t)(m0 + wm * 128 + mq * 64 + j * 16 + lk * 4 + r) * 1024 +
                    n0 + wn * 64 + ni * 16 + lr);
  } else {
    // dots epilogue: wave's 64 cols = head h; stage k[128 rows][64] from kb [M,1024]
    // into LDS with XOR swizzle (pre-swizzled source, swizzled read -> 2-way max),
    // dot with acc along cols, width-16 shfl reduce, write dots[row, h].
    const int h = (n0 >> 6) + wn;
    ushort_t* kw = lds + w * 8192;
    const int rsub = lane >> 3;
    const int csw = (((lane & 7) * 16) ^ (rsub << 4)) >> 1;   // swizzled src col (elems)
    const ushort_t* kS = kvp + (size_t)(m0 + wm * 128 + rsub) * 1024 + h * 64 + csw;
#pragma unroll
    for (int i = 0; i < 16; ++i)
      lds_load16(kS + (size_t)i * 8 * 1024, kw + i * 512);
    asm volatile("s_waitcnt vmcnt(0)" ::: "memory");
#pragma unroll
    for (int mq = 0; mq < 2; ++mq)
#pragma unroll
      for (int j = 0; j < 4; ++j)
#pragma unroll
        for (int r = 0; r < 4; ++r) {
          const int row = mq * 64 + j * 16 + lk * 4 + r;
          float p = 0.f;
#pragma unroll
          for (int ni = 0; ni < 4; ++ni) {
            const int ce = (((ni * 16 + lr) * 2) ^ ((row & 7) << 4)) >> 1;
            p += acc[mq * 4 + j][ni][r] * bf2f(kw[row * 64 + ce]);
          }
#pragma unroll
          for (int off = 1; off < 16; off <<= 1) p += __shfl_xor(p, off, 16);
          if (lr == 0)
            dots[(size_t)(m0 + wm * 128 + row) * 16 + h] = p * 0.015625f;
        }
  }
}

extern "C" void kernel_launch(void* const* d_in, const int* in_sizes, int n_in,
                              void* d_out, int out_size, void* d_ws, size_t ws_size,
                              hipStream_t stream) {
  const float* x   = (const float*)d_in[0];
  const float* y   = (const float*)d_in[1];
  const float* Wq  = (const float*)d_in[3];
  const float* Wkv = (const float*)d_in[4];
  const float* Wp  = (const float*)d_in[5];
  const float* bp  = (const float*)d_in[6];
  (void)in_sizes; (void)n_in; (void)out_size; (void)ws_size;

  char* ws = (char*)d_ws;                               // 396 MiB total
  ushort_t* Wall  = (ushort_t*)(ws);                    //   8 MiB [4096][1024] = [Wq|Wk|Wv|Wp]
  float*    dotsb = (float*)   (ws + (8ull   << 20));   //   4 MiB [65536][16] dots->attn
  ushort_t* yb    = (ushort_t*)(ws + (12ull  << 20));   // 128 MiB y bf16 (alive thru v-gemm)
  ushort_t* xb    = (ushort_t*)(ws + (140ull << 20));   // 128 MiB x bf16 -> reused as ab
  ushort_t* kb    = (ushort_t*)(ws + (268ull << 20));   // 128 MiB k bf16

  const ushort_t* Wqt = Wall;
  const ushort_t* Wkt = Wall + (size_t)1024 * 1024;
  const ushort_t* Wvt = Wall + (size_t)2048 * 1024;
  const ushort_t* Wpt = Wall + (size_t)3072 * 1024;

  // all weights -> bf16, transposed, one launch
  wtrans4<<<dim3(128, 32), 256, 0, stream>>>(Wq, Wkv, Wp, Wall);

  // x,y -> bf16 in one launch (round-10 proven form)
  cvt2<<<8192, 256, 0, stream>>>(x, y, xb, yb);

  // k = yb @ Wk
  gemm8<0><<<1024, 512, 0, stream>>>(yb, Wkt, kb, nullptr, nullptr, nullptr, 1024, 2);

  // dots = per-head <q, k>: q-GEMM with fused dots epilogue (q never materialized)
  gemm8<2><<<1024, 512, 0, stream>>>(xb, Wqt, nullptr, nullptr, kb, dotsb, 1024, 2);

  // softmax over heads, in place
  softmax16<<<256, 256, 0, stream>>>(dotsb);

  // ab = attn .* (yb @ Wv)   — v never materialized unscaled
  gemm8<3><<<1024, 512, 0, stream>>>(yb, Wvt, xb, dotsb, nullptr, nullptr, 1024, 2);

  // out = ab @ Wproj + bproj (f32, nontemporal stores)
  gemm8<1><<<1024, 512, 0, stream>>>(xb, Wpt, d_out, bp, nullptr, nullptr, 1024, 2);
}